// Round 1
// baseline (316.971 us; speedup 1.0000x reference)
//
#include <hip/hip_runtime.h>
#include <hip/hip_bf16.h>
#include <cstdint>

typedef __bf16 bf16;
typedef __bf16 bf16x8 __attribute__((ext_vector_type(8)));
typedef float floatx4 __attribute__((ext_vector_type(4)));

#define B_   4
#define L_   896
#define D_   2048
#define HQ_  32
#define HKV_ 8
#define HD_  64
#define NQKV 3072   /* 2048 q + 512 k + 512 v */
#define M_   3584   /* B_*L_ */

// async global->LDS, 16B per lane. LDS dst must be wave-uniform base + lane*16.
__device__ inline void gl_lds16(const bf16* g, bf16* l) {
    __builtin_amdgcn_global_load_lds(
        (const __attribute__((address_space(1))) void*)g,
        (__attribute__((address_space(3))) void*)l, 16, 0, 0);
}

__device__ inline void barrier_() {
    asm volatile("" ::: "memory");
    __builtin_amdgcn_s_barrier();
    asm volatile("" ::: "memory");
}

// ---------------------------------------------------------------------------
// fp32 -> bf16 (x only). Grid: n/1024 blocks.
// ---------------------------------------------------------------------------
__global__ __launch_bounds__(256) void convert_to_bf16(const float* __restrict__ in,
                                                       bf16* __restrict__ out) {
    long q = (long)blockIdx.x * 256 + threadIdx.x;
    float4 v = ((const float4*)in)[q];
    union { bf16 b[4]; ushort4 u; } w;
    w.b[0] = (bf16)v.x; w.b[1] = (bf16)v.y; w.b[2] = (bf16)v.z; w.b[3] = (bf16)v.w;
    ((ushort4*)out)[q] = w.u;
}

// ---------------------------------------------------------------------------
// RoPE cos/sin table: [L][32] float2
// ---------------------------------------------------------------------------
__global__ __launch_bounds__(256) void rope_cs_kernel(const int* __restrict__ pos_ids,
                                                      float2* __restrict__ cs) {
    int idx = blockIdx.x * 256 + threadIdx.x;
    if (idx >= L_ * 32) return;
    int l = idx >> 5, i = idx & 31;
    float p = (float)pos_ids[l];
    float inv = exp2f(-(float)i * (13.287712379549449f / 32.0f));  // 10000^(-i/32)
    float a = p * inv;
    cs[idx] = make_float2(cosf(a), sinf(a));
}

// ---------------------------------------------------------------------------
// Standalone RoPE, vectorized: 4 pairs (16 B) per thread, in place on
// QKV cols [0,2560). Grid: 3584*320/256 = 4480 blocks.
// ---------------------------------------------------------------------------
__global__ __launch_bounds__(256) void rope_apply(bf16* __restrict__ QKV,
                                                  const float2* __restrict__ cs) {
    int idx = blockIdx.x * 256 + threadIdx.x;   // [0, 3584*320)
    int m = idx / 320, g = idx - m * 320;       // 4-pair group; cols 8g..8g+7
    int l = m % L_;
    int hp = (g * 4) & 31;                      // head-local pair idx of pair0
    const float2* ct = &cs[l * 32 + hp];
    bf16* p = QKV + (long)m * NQKV + g * 8;
    bf16x8 v = *(bf16x8*)p;
    bf16x8 w;
#pragma unroll
    for (int i = 0; i < 4; i++) {
        float2 csv = ct[i];
        float x1 = (float)v[2 * i], x2 = (float)v[2 * i + 1];
        w[2 * i]     = (bf16)(x1 * csv.x - x2 * csv.y);
        w[2 * i + 1] = (bf16)(x1 * csv.y + x2 * csv.x);
    }
    *(bf16x8*)p = w;
}

// ---------------------------------------------------------------------------
// Fused fp32->bf16 + 64x64 tiled transpose. in fp32 [R][C] -> out bf16 [C][R].
// ---------------------------------------------------------------------------
__global__ __launch_bounds__(256) void transpose_cvt(
    const float* __restrict__ in, ushort* __restrict__ out, int C, int R) {
    __shared__ ushort t[64][72];
    int tid = threadIdx.x;
    int tr = tid >> 4, tc = (tid & 15) << 2;
    long r0 = (long)blockIdx.y << 6, c0 = (long)blockIdx.x << 6;
#pragma unroll
    for (int i = 0; i < 4; ++i) {
        float4 v = *(const float4*)&in[(r0 + tr + i * 16) * C + c0 + tc];
        union { bf16 b[4]; ushort4 u; } w;
        w.b[0] = (bf16)v.x; w.b[1] = (bf16)v.y; w.b[2] = (bf16)v.z; w.b[3] = (bf16)v.w;
        *(ushort4*)&t[tr + i * 16][tc] = w.u;
    }
    __syncthreads();
#pragma unroll
    for (int i = 0; i < 4; ++i) {
        ushort4 w;
        w.x = t[tc + 0][tr + i * 16];
        w.y = t[tc + 1][tr + i * 16];
        w.z = t[tc + 2][tr + i * 16];
        w.w = t[tc + 3][tr + i * 16];
        *(ushort4*)&out[(c0 + tr + i * 16) * R + r0 + tc] = w;
    }
}

// ---------------------------------------------------------------------------
// bf16 64x64 tiled transpose (for V -> Vt). z-batch as before.
// ---------------------------------------------------------------------------
__global__ __launch_bounds__(256) void transpose_u16(
    const ushort* __restrict__ in, ushort* __restrict__ out,
    int ld_in, int ld_out, long is1, long is2, long os1, long os2) {
    __shared__ ushort t[64][72];
    int z = blockIdx.z;
    const ushort* ip = in + (long)(z >> 3) * is1 + (long)(z & 7) * is2;
    ushort* op = out + (long)(z >> 3) * os1 + (long)(z & 7) * os2;
    int tid = threadIdx.x;
    int tr = tid >> 4, tc = (tid & 15) << 2;
    long r0 = (long)blockIdx.y << 6, c0 = (long)blockIdx.x << 6;
#pragma unroll
    for (int i = 0; i < 4; ++i) {
        ushort4 v = *(const ushort4*)&ip[(r0 + tr + i * 16) * ld_in + c0 + tc];
        *(ushort4*)&t[tr + i * 16][tc] = v;
    }
    __syncthreads();
#pragma unroll
    for (int i = 0; i < 4; ++i) {
        ushort4 w;
        w.x = t[tc + 0][tr + i * 16];
        w.y = t[tc + 1][tr + i * 16];
        w.z = t[tc + 2][tr + i * 16];
        w.w = t[tc + 3][tr + i * 16];
        *(ushort4*)&op[(c0 + tr + i * 16) * ld_out + r0 + tc] = w;
    }
}

// ===========================================================================
// 256x256 8-phase GEMM (m201-style): C[M][N] = A[M][K] * Bt[N][K]^T.
// 8 waves (2Mx4N), BK=64, 128 KiB double-buffered LDS, st_16x32 XOR swizzle
// via pre-swizzled global source + swizzled ds_read, counted vmcnt, setprio.
//
// LDS halves: A-half h = tile rows [h*128,+128) x 64 k-cols, row-major [128][64],
// B-half h likewise for Bt rows. Swizzle (within 1024B subtile = 8 rows):
//   phys_byte = log_byte ^ (((log_byte>>9)&1)<<5)  -> col ^= ((row&4)?16:0).
//
// Phase schedule per K-tile t (buf cur=t&1), staging 1 half-tile per phase:
//   p1: ldA(q0)+ldB(q0) | stage (t+1).A0 -> nxt | MFMA quad(r0,c0)
//   p2: ldB(q1)         | stage (t+1).A1 -> nxt | MFMA quad(r0,c1)
//   p3: ldA(q1)         | stage (t+2).B0 -> cur | MFMA quad(r1,c0)
//   p4:                 | stage (t+2).B1 -> cur | MFMA quad(r1,c1); vmcnt(4)
// Overwrite safety: A-halves last read at p3 -> overwritten at next p1/p2;
// B-halves last read at p2 -> overwritten at p3/p4. vmcnt(4) at p4 leaves only
// (t+2).B0/B1 in flight => tile t+1 fully landed before its p1.
// ===========================================================================

template <int RQ>
__device__ inline void lda(const bf16* p, int l16, int colA, bf16x8 (&af)[4][2]) {
#pragma unroll
    for (int i = 0; i < 4; ++i)
#pragma unroll
        for (int ks = 0; ks < 2; ++ks)
            af[i][ks] = *(const bf16x8*)&p[(RQ * 64 + i * 16 + l16) * 64 + ks * 32 + colA];
}

template <int CQ>
__device__ inline void ldb(const bf16* p, int brow, int l16, int colA, bf16x8 (&bq)[2][2]) {
#pragma unroll
    for (int j = 0; j < 2; ++j)
#pragma unroll
        for (int ks = 0; ks < 2; ++ks)
            bq[j][ks] = *(const bf16x8*)&p[(brow + (CQ * 2 + j) * 16 + l16) * 64 + ks * 32 + colA];
}

template <int RQ, int CQ>
__device__ inline void mma(const bf16x8 (&af)[4][2], const bf16x8 (&bq)[2][2],
                           floatx4 (&acc)[8][4]) {
#pragma unroll
    for (int i = 0; i < 4; ++i)
#pragma unroll
        for (int j = 0; j < 2; ++j) {
            floatx4 c = acc[RQ * 4 + i][CQ * 2 + j];
            c = __builtin_amdgcn_mfma_f32_16x16x32_bf16(af[i][0], bq[j][0], c, 0, 0, 0);
            c = __builtin_amdgcn_mfma_f32_16x16x32_bf16(af[i][1], bq[j][1], c, 0, 0, 0);
            acc[RQ * 4 + i][CQ * 2 + j] = c;
        }
}

__device__ inline void stage_half(const bf16* gsrc, bf16* ldst, long rowK) {
    gl_lds16(gsrc,            ldst);
    gl_lds16(gsrc + 8 * rowK, ldst + 512);
}

__global__ __launch_bounds__(512, 2) void gemm256(
    const bf16* __restrict__ A, const bf16* __restrict__ Bt, void* __restrict__ C,
    int Ntot, int Ktot, int outf32) {
    __shared__ bf16 lds[2][2][2][128 * 64];   // [buf][A/B][half][r*64+c] = 128 KiB
    const int tid = threadIdx.x;
    const int w = tid >> 6, lane = tid & 63;
    const int quad = lane >> 4, l16 = lane & 15;
    const int wr = w >> 2, wc = w & 3;

    // XCD-aware bijective swizzle (T1)
    const int gx = gridDim.x;
    const int nwg = gx * gridDim.y;
    int orig = blockIdx.y * gx + blockIdx.x;
    int q8 = nwg >> 3, r8 = nwg & 7;
    int xcd = orig & 7, lid = orig >> 3;
    int wg = (xcd < r8 ? xcd * (q8 + 1) : r8 * (q8 + 1) + (xcd - r8) * q8) + lid;
    const long m0 = (long)(wg / gx) << 8;
    const long n0 = (long)(wg % gx) << 8;

    // staging: lane's pre-swizzled source granule within its 1024B subtile
    const long rowK = Ktot;
    const int sl = lane ^ ((lane & 32) >> 4);       // swap granule bit1 with byte bit9
    const int srow = w * 16 + (sl >> 3);            // row within half for chunk0
    const int scol = (sl & 7) * 8;
    const bf16* baseA = A  + (m0 + srow) * rowK + scol;
    const bf16* baseB = Bt + (n0 + srow) * rowK + scol;
    const int d0 = w * 1024 + lane * 8;             // LDS elems (lane*16B)

    // ds_read swizzle: col ^= 16 when (row&4)
    const int cswz = (l16 & 4) << 2;
    const int colA = (quad * 8) ^ cswz;
    const int brow = (wc & 1) * 64;

    floatx4 acc[8][4];
#pragma unroll
    for (int i = 0; i < 8; ++i)
#pragma unroll
        for (int j = 0; j < 4; ++j)
#pragma unroll
            for (int r = 0; r < 4; ++r) acc[i][j][r] = 0.f;

    bf16x8 af[4][2], bq0[2][2], bq1[2][2];

    const int T = Ktot >> 6;
    // prologue: tile0 {A0,A1,B0,B1} -> buf0; tile1 {B0,B1} -> buf1
    stage_half(baseA,                   &lds[0][0][0][d0], rowK);
    stage_half(baseA + 128 * rowK,      &lds[0][0][1][d0], rowK);
    stage_half(baseB,                   &lds[0][1][0][d0], rowK);
    stage_half(baseB + 128 * rowK,      &lds[0][1][1][d0], rowK);
    stage_half(baseB + 64,              &lds[1][1][0][d0], rowK);
    stage_half(baseB + 128 * rowK + 64, &lds[1][1][1][d0], rowK);
    asm volatile("s_waitcnt vmcnt(4)" ::: "memory");   // tile0 landed
    barrier_();

    for (int t = 0; t < T; ++t) {
        const int cur = t & 1, nxt = cur ^ 1;
        const bf16* pa = &lds[cur][0][wr][0];
        const bf16* pb = &lds[cur][1][wc >> 1][0];
        const long koff  = (long)(t + 1) * 64;
        const long koff2 = (long)(t + 2) * 64;

        // ---- phase 1: A q0 + B q0 | stage (t+1).A0 ----
        lda<0>(pa, l16, colA, af);
        ldb<0>(pb, brow, l16, colA, bq0);
        if (t + 1 < T) stage_half(baseA + koff, &lds[nxt][0][0][d0], rowK);
        barrier_();
        asm volatile("s_waitcnt lgkmcnt(0)" ::: "memory");
        __builtin_amdgcn_sched_barrier(0);
        __builtin_amdgcn_s_setprio(1);
        mma<0, 0>(af, bq0, acc);
        __builtin_amdgcn_s_setprio(0);
        barrier_();

        // ---- phase 2: B q1 | stage (t+1).A1 ----
        ldb<1>(pb, brow, l16, colA, bq1);
        if (t + 1 < T) stage_half(baseA + 128 * rowK + koff, &lds[nxt][0][1][d0], rowK);
        barrier_();
        asm volatile("s_waitcnt lgkmcnt(0)" ::: "memory");
        __builtin_amdgcn_sched_barrier(0);
        __builtin_amdgcn_s_setprio(1);
        mma<0, 1>(af, bq1, acc);
        __builtin_amdgcn_s_setprio(0);
        barrier_();

        // ---- phase 3: A q1 | stage (t+2).B0 ----
        lda<1>(pa, l16, colA, af);
        if (t + 2 < T) stage_half(baseB + koff2, &lds[cur][1][0][d0], rowK);
        barrier_();
        asm volatile("s_waitcnt lgkmcnt(0)" ::: "memory");
        __builtin_amdgcn_sched_barrier(0);
        __builtin_amdgcn_s_setprio(1);
        mma<1, 0>(af, bq0, acc);
        __builtin_amdgcn_s_setprio(0);
        barrier_();

        // ---- phase 4: stage (t+2).B1 | counted vmcnt ----
        if (t + 2 < T) stage_half(baseB + 128 * rowK + koff2, &lds[cur][1][1][d0], rowK);
        barrier_();
        asm volatile("s_waitcnt lgkmcnt(0)" ::: "memory");
        __builtin_amdgcn_sched_barrier(0);
        __builtin_amdgcn_s_setprio(1);
        mma<1, 1>(af, bq1, acc);
        __builtin_amdgcn_s_setprio(0);
        if (t + 2 < T) asm volatile("s_waitcnt vmcnt(4)" ::: "memory");
        else           asm volatile("s_waitcnt vmcnt(0)" ::: "memory");
        barrier_();
    }

    // epilogue: C/D layout row = quad*4 + r, col = l16
#pragma unroll
    for (int ri = 0; ri < 8; ++ri)
#pragma unroll
        for (int j = 0; j < 4; ++j)
#pragma unroll
            for (int r = 0; r < 4; ++r) {
                long m = m0 + wr * 128 + ri * 16 + quad * 4 + r;
                long n = n0 + wc * 64 + j * 16 + l16;
                if (outf32) ((float*)C)[m * Ntot + n] = acc[ri][j][r];
                else        ((bf16*)C)[m * Ntot + n] = (bf16)acc[ri][j][r];
            }
}

// ---------------------------------------------------------------------------
// Flash attention v3: block-cooperative LDS staging of K/V tiles.
// Block = 4 waves sharing (b,hq); wave w owns q-rows [q0b + 16w, +16).
// Per 64-key tile: stage K[64][64]->Ks (pad 72), V[64dim][64key]->Vs (pad 72)
// with coalesced loads; all waves read MFMA fragments from LDS.
// Fixed-max softmax: p = exp(s/8 - 12) (scores bounded, no online rescale).
// ---------------------------------------------------------------------------
__global__ __launch_bounds__(256) void attn_kernel(
    const bf16* __restrict__ QKV,  // [M][3072]: q(rope'd) | k(rope'd) | v
    const bf16* __restrict__ Vt,   // [B][HKV][64][896]
    bf16* __restrict__ AO) {       // [M][2048]
    __shared__ bf16 Ks[64 * 72];
    __shared__ bf16 Vs[64 * 72];
    __shared__ bf16 Ps[4][16 * 72];
    const int tid  = threadIdx.x;
    const int wid  = tid >> 6, lane = tid & 63;
    const int quad = lane >> 4, c = lane & 15;
    const int b = blockIdx.z, hq = blockIdx.y, kvh = hq >> 2;
    const int q0b = blockIdx.x * 64;
    const int q0 = q0b + wid * 16;
    bf16* ps = &Ps[wid][0];

    const bf16* Qb = QKV + ((long)(b * L_ + q0)) * NQKV + hq * HD_;
    const bf16* Kb = QKV + ((long)(b * L_)) * NQKV + D_ + kvh * HD_;
    const bf16* Vb = Vt + ((long)(b * HKV_ + kvh)) * (HD_ * L_);

    bf16x8 qf0 = *(const bf16x8*)&Qb[(long)c * NQKV + quad * 8];
    bf16x8 qf1 = *(const bf16x8*)&Qb[(long)c * NQKV + 32 + quad * 8];

    float lsum[4];
    floatx4 o[4];
#pragma unroll
    for (int r = 0; r < 4; r++) lsum[r] = 0.f;
#pragma unroll
    for (int nt = 0; nt < 4; nt++)
#pragma unroll
        for (int r = 0; r < 4; r++) o[nt][r] = 0.f;

    int fe[4];  // exclusive frame-end per owned row (rows quad*4+r)
#pragma unroll
    for (int r = 0; r < 4; r++) { int l = q0 + quad * 4 + r; fe[r] = (l / 7 + 1) * 7; }
    const int kend = ((q0b + 63) / 7 + 1) * 7;   // block-max frame end, <= 896

    // staging coords: thread stages 16 B at rows srow / srow+32, chunk schunk
    const int srow = tid >> 3, schunk = (tid & 7) << 3;

    for (int k0 = 0; k0 < kend; k0 += 64) {
        // coalesced global loads (1 KB contiguous per wave per load)
        bf16x8 kg0 = *(const bf16x8*)&Kb[(long)(k0 + srow) * NQKV + schunk];
        bf16x8 kg1 = *(const bf16x8*)&Kb[(long)(k0 + 32 + srow) * NQKV + schunk];
        bf16x8 vg0 = *(const bf16x8*)&Vb[(long)srow * L_ + k0 + schunk];
        bf16x8 vg1 = *(const bf16x8*)&Vb[(long)(srow + 32) * L_ + k0 + schunk];
        __syncthreads();   // previous tile's reads done before overwrite
        *(bf16x8*)&Ks[srow * 72 + schunk]        = kg0;
        *(bf16x8*)&Ks[(srow + 32) * 72 + schunk] = kg1;
        *(bf16x8*)&Vs[srow * 72 + schunk]        = vg0;
        *(bf16x8*)&Vs[(srow + 32) * 72 + schunk] = vg1;
        __syncthreads();

        // QK^T: B-frag b[j] = K[key = n*16+c][d = quad*8+j (+32)]
        floatx4 s[4];
#pragma unroll
        for (int n = 0; n < 4; n++) {
#pragma unroll
            for (int r = 0; r < 4; r++) s[n][r] = 0.f;
            bf16x8 kf0 = *(bf16x8*)&Ks[(n * 16 + c) * 72 + quad * 8];
            bf16x8 kf1 = *(bf16x8*)&Ks[(n * 16 + c) * 72 + 32 + quad * 8];
            s[n] = __builtin_amdgcn_mfma_f32_16x16x32_bf16(qf0, kf0, s[n], 0, 0, 0);
            s[n] = __builtin_amdgcn_mfma_f32_16x16x32_bf16(qf1, kf1, s[n], 0, 0, 0);
        }
        // fixed-max softmax: p = exp(s/8 - 12); masked -> 0
#pragma unroll
        for (int n = 0; n < 4; n++) {
            const int key = k0 + n * 16 + c;
#pragma unroll
            for (int r = 0; r < 4; r++) {
                float e = __expf(fmaf(s[n][r], 0.125f, -12.0f));
                e = (key < fe[r]) ? e : 0.f;
                lsum[r] += e;
                ps[(quad * 4 + r) * 72 + n * 16 + c] = (bf16)e;
            }
        }
        // P A-frags (same-wave LDS round-trip) + PV from Vs
        bf16x8 pf0 = *(bf16x8*)&ps[c * 72 + quad * 8];
        bf16x8 pf1 = *(bf16x8*)&ps[c * 72 + 32 + quad * 8];
#pragma unroll
        for (int nt = 0; nt < 4; nt++) {
            bf16x8 vf0 = *(bf16x8*)&Vs[(nt * 16 + c) * 72 + quad * 8];
            bf16x8 vf1 = *(bf16x8*)&Vs[(nt * 16 + c) * 72 + 32 + quad * 8];
            o[nt] = __builtin_amdgcn_mfma_f32_16x16x32_bf16(pf0, vf0, o[nt], 0, 0, 0);
            o[nt] = __builtin_amdgcn_mfma_f32_16x16x32_bf16(pf1, vf1, o[nt], 0, 0, 0);
        }
    }
    // one cross-lane lsum reduction over the 16 c-lanes
#pragma unroll
    for (int r = 0; r < 4; r++) {
#pragma unroll
        for (int off = 1; off < 16; off <<= 1) lsum[r] += __shfl_xor(lsum[r], off);
    }
#pragma unroll
    for (int nt = 0; nt < 4; nt++)
#pragma unroll
        for (int r = 0; r < 4; r++) {
            int l = q0 + quad * 4 + r;
            AO[((long)(b * L_ + l)) * D_ + hq * HD_ + nt * 16 + c] = (bf16)(o[nt][r] / lsum[r]);
        }
}

// ---------------------------------------------------------------------------
extern "C" void kernel_launch(void* const* d_in, const int* in_sizes, int n_in,
                              void* d_out, int out_size, void* d_ws, size_t ws_size,
                              hipStream_t stream) {
    (void)in_sizes; (void)n_in; (void)out_size; (void)ws_size;
    const float* x  = (const float*)d_in[0];
    const float* wq = (const float*)d_in[1];
    const float* wk = (const float*)d_in[2];
    const float* wv = (const float*)d_in[3];
    const float* wo = (const float*)d_in[4];
    const int* pos  = (const int*)d_in[5];

    bf16* ws    = (bf16*)d_ws;
    bf16* xb    = ws;                   // [3584][2048] bf16 x  (reused as AO)
    bf16* wqkvT = ws + 7340032L;        // [3072][2048]  (wq^T | wk^T | wv^T)
    bf16* woT   = ws + 13631488L;       // [2048][2048]
    bf16* QKV   = ws + 17825792L;       // [3584][3072]
    bf16* Vt    = ws + 28835840L;       // [4][8][64][896]
    bf16* AO    = xb;
    float2* cs  = (float2*)(ws + 30670848L);  // [896][32]

    convert_to_bf16<<<dim3(7168), 256, 0, stream>>>(x, xb);
    rope_cs_kernel<<<dim3(112), dim3(256), 0, stream>>>(pos, cs);

    transpose_cvt<<<dim3(32, 32), 256, 0, stream>>>(wq, (ushort*)wqkvT, 2048, 2048);
    transpose_cvt<<<dim3(8, 32), 256, 0, stream>>>(wk, (ushort*)(wqkvT + 4194304L), 512, 2048);
    transpose_cvt<<<dim3(8, 32), 256, 0, stream>>>(wv, (ushort*)(wqkvT + 5242880L), 512, 2048);
    transpose_cvt<<<dim3(32, 32), 256, 0, stream>>>(wo, (ushort*)woT, 2048, 2048);

    // QKV projection: [3584][2048] x [3072][2048]^T -> [3584][3072] bf16
    gemm256<<<dim3(12, 14), 512, 0, stream>>>(xb, wqkvT, QKV, NQKV, D_, 0);

    rope_apply<<<dim3(4480), 256, 0, stream>>>(QKV, cs);

    // V cols of QKV -> Vt[b][h][64][896]
    transpose_u16<<<dim3(1, 14, 32), 256, 0, stream>>>(
        (const ushort*)(QKV + 2560), (ushort*)Vt, 3072, 896,
        896L * 3072, 64, 8L * 57344, 57344);

    attn_kernel<<<dim3(14, 32, 4), 256, 0, stream>>>(QKV, Vt, AO);

    // output projection: [3584][2048] x [2048][2048]^T -> [3584][2048] fp32
    gemm256<<<dim3(8, 14), 512, 0, stream>>>(AO, woT, d_out, D_, D_, 1);
}

// Round 2
// 302.330 us; speedup vs baseline: 1.0484x; 1.0484x over previous
//
#include <hip/hip_runtime.h>
#include <hip/hip_bf16.h>
#include <cstdint>

typedef __bf16 bf16;
typedef __bf16 bf16x8 __attribute__((ext_vector_type(8)));
typedef float floatx4 __attribute__((ext_vector_type(4)));

#define B_   4
#define L_   896
#define D_   2048
#define HQ_  32
#define HKV_ 8
#define HD_  64
#define NQKV 3072   /* 2048 q + 512 k + 512 v */
#define M_   3584   /* B_*L_ */

// async global->LDS, 16B per lane. LDS dst must be wave-uniform base + lane*16.
__device__ inline void gl_lds16(const bf16* g, bf16* l) {
    __builtin_amdgcn_global_load_lds(
        (const __attribute__((address_space(1))) void*)g,
        (__attribute__((address_space(3))) void*)l, 16, 0, 0);
}

__device__ inline void barrier_() {
    asm volatile("" ::: "memory");
    __builtin_amdgcn_s_barrier();
    asm volatile("" ::: "memory");
}

// ---------------------------------------------------------------------------
// fp32 -> bf16 (x only). Grid: n/1024 blocks.
// ---------------------------------------------------------------------------
__global__ __launch_bounds__(256) void convert_to_bf16(const float* __restrict__ in,
                                                       bf16* __restrict__ out) {
    long q = (long)blockIdx.x * 256 + threadIdx.x;
    float4 v = ((const float4*)in)[q];
    union { bf16 b[4]; ushort4 u; } w;
    w.b[0] = (bf16)v.x; w.b[1] = (bf16)v.y; w.b[2] = (bf16)v.z; w.b[3] = (bf16)v.w;
    ((ushort4*)out)[q] = w.u;
}

// ---------------------------------------------------------------------------
// RoPE cos/sin table: [L][32] float2
// ---------------------------------------------------------------------------
__global__ __launch_bounds__(256) void rope_cs_kernel(const int* __restrict__ pos_ids,
                                                      float2* __restrict__ cs) {
    int idx = blockIdx.x * 256 + threadIdx.x;
    if (idx >= L_ * 32) return;
    int l = idx >> 5, i = idx & 31;
    float p = (float)pos_ids[l];
    float inv = exp2f(-(float)i * (13.287712379549449f / 32.0f));  // 10000^(-i/32)
    float a = p * inv;
    cs[idx] = make_float2(cosf(a), sinf(a));
}

// ---------------------------------------------------------------------------
// Standalone RoPE, vectorized: 4 pairs (16 B) per thread, in place on
// QKV cols [0,2560). Grid: 3584*320/256 = 4480 blocks.
// ---------------------------------------------------------------------------
__global__ __launch_bounds__(256) void rope_apply(bf16* __restrict__ QKV,
                                                  const float2* __restrict__ cs) {
    int idx = blockIdx.x * 256 + threadIdx.x;   // [0, 3584*320)
    int m = idx / 320, g = idx - m * 320;       // 4-pair group; cols 8g..8g+7
    int l = m % L_;
    int hp = (g * 4) & 31;                      // head-local pair idx of pair0
    const float2* ct = &cs[l * 32 + hp];
    bf16* p = QKV + (long)m * NQKV + g * 8;
    bf16x8 v = *(bf16x8*)p;
    bf16x8 w;
#pragma unroll
    for (int i = 0; i < 4; i++) {
        float2 csv = ct[i];
        float x1 = (float)v[2 * i], x2 = (float)v[2 * i + 1];
        w[2 * i]     = (bf16)(x1 * csv.x - x2 * csv.y);
        w[2 * i + 1] = (bf16)(x1 * csv.y + x2 * csv.x);
    }
    *(bf16x8*)p = w;
}

// ---------------------------------------------------------------------------
// Fused fp32->bf16 + 64x64 tiled transpose. in fp32 [R][C] -> out bf16 [C][R].
// ---------------------------------------------------------------------------
__global__ __launch_bounds__(256) void transpose_cvt(
    const float* __restrict__ in, ushort* __restrict__ out, int C, int R) {
    __shared__ ushort t[64][72];
    int tid = threadIdx.x;
    int tr = tid >> 4, tc = (tid & 15) << 2;
    long r0 = (long)blockIdx.y << 6, c0 = (long)blockIdx.x << 6;
#pragma unroll
    for (int i = 0; i < 4; ++i) {
        float4 v = *(const float4*)&in[(r0 + tr + i * 16) * C + c0 + tc];
        union { bf16 b[4]; ushort4 u; } w;
        w.b[0] = (bf16)v.x; w.b[1] = (bf16)v.y; w.b[2] = (bf16)v.z; w.b[3] = (bf16)v.w;
        *(ushort4*)&t[tr + i * 16][tc] = w.u;
    }
    __syncthreads();
#pragma unroll
    for (int i = 0; i < 4; ++i) {
        ushort4 w;
        w.x = t[tc + 0][tr + i * 16];
        w.y = t[tc + 1][tr + i * 16];
        w.z = t[tc + 2][tr + i * 16];
        w.w = t[tc + 3][tr + i * 16];
        *(ushort4*)&out[(c0 + tr + i * 16) * R + r0 + tc] = w;
    }
}

// ---------------------------------------------------------------------------
// bf16 64x64 tiled transpose (for V -> Vt). z-batch as before.
// ---------------------------------------------------------------------------
__global__ __launch_bounds__(256) void transpose_u16(
    const ushort* __restrict__ in, ushort* __restrict__ out,
    int ld_in, int ld_out, long is1, long is2, long os1, long os2) {
    __shared__ ushort t[64][72];
    int z = blockIdx.z;
    const ushort* ip = in + (long)(z >> 3) * is1 + (long)(z & 7) * is2;
    ushort* op = out + (long)(z >> 3) * os1 + (long)(z & 7) * os2;
    int tid = threadIdx.x;
    int tr = tid >> 4, tc = (tid & 15) << 2;
    long r0 = (long)blockIdx.y << 6, c0 = (long)blockIdx.x << 6;
#pragma unroll
    for (int i = 0; i < 4; ++i) {
        ushort4 v = *(const ushort4*)&ip[(r0 + tr + i * 16) * ld_in + c0 + tc];
        *(ushort4*)&t[tr + i * 16][tc] = v;
    }
    __syncthreads();
#pragma unroll
    for (int i = 0; i < 4; ++i) {
        ushort4 w;
        w.x = t[tc + 0][tr + i * 16];
        w.y = t[tc + 1][tr + i * 16];
        w.z = t[tc + 2][tr + i * 16];
        w.w = t[tc + 3][tr + i * 16];
        *(ushort4*)&op[(c0 + tr + i * 16) * ld_out + r0 + tc] = w;
    }
}

// ===========================================================================
// 256x256 8-phase GEMM (m201-style): C[M][N] = A[M][K] * Bt[N][K]^T.
// 8 waves (2Mx4N), BK=64, 128 KiB double-buffered LDS, counted vmcnt, setprio.
//
// LDS halves: A-half h = tile rows [h*128,+128) x 64 k-cols, row-major [128][64]
// bf16 (128 B rows = exactly 32 banks). 3-bit slot swizzle (G4 form):
//   a row is 8 x 16B slots; phys_slot = log_slot ^ (row & 7).
// Read side: fragment (row, ks*32+quad*8) -> col = ((ks*4+quad)^(row&7))<<3.
//   Each quad's 16 lanes (rows l16, row&7 = l16&7) fan over all 8 slots:
//   2 lanes/slot (free), full wave = 8 lanes per 4-bank group = conflict-free.
// Write side (rule #21: both-sides-or-neither): gl_lds writes linearly, so
//   lane l sources global (row = 16w + (l>>3), col = ((l&7)^(l>>3))<<3).
//   Both stage_half chunks are +8 rows (== 0 mod 8) -> same lane offset.
//
// Phase schedule per K-tile t (buf cur=t&1), staging 1 half-tile per phase:
//   p1: ldA(q0)+ldB(q0) | stage (t+1).A0 -> nxt | MFMA quad(r0,c0)
//   p2: ldB(q1)         | stage (t+1).A1 -> nxt | MFMA quad(r0,c1)
//   p3: ldA(q1)         | stage (t+2).B0 -> cur | MFMA quad(r1,c0)
//   p4:                 | stage (t+2).B1 -> cur | MFMA quad(r1,c1); vmcnt(4)
// Overwrite safety: A-halves last read at p3 -> overwritten at next p1/p2;
// B-halves last read at p2 -> overwritten at p3/p4. vmcnt(4) at p4 leaves only
// (t+2).B0/B1 in flight => tile t+1 fully landed before its p1.
// ===========================================================================

template <int RQ>
__device__ inline void lda(const bf16* p, int l16, int c0, int c1, bf16x8 (&af)[4][2]) {
#pragma unroll
    for (int i = 0; i < 4; ++i) {
        const bf16* rp = &p[(RQ * 64 + i * 16 + l16) * 64];
        af[i][0] = *(const bf16x8*)&rp[c0];
        af[i][1] = *(const bf16x8*)&rp[c1];
    }
}

template <int CQ>
__device__ inline void ldb(const bf16* p, int brow, int l16, int c0, int c1,
                           bf16x8 (&bq)[2][2]) {
#pragma unroll
    for (int j = 0; j < 2; ++j) {
        const bf16* rp = &p[(brow + (CQ * 2 + j) * 16 + l16) * 64];
        bq[j][0] = *(const bf16x8*)&rp[c0];
        bq[j][1] = *(const bf16x8*)&rp[c1];
    }
}

template <int RQ, int CQ>
__device__ inline void mma(const bf16x8 (&af)[4][2], const bf16x8 (&bq)[2][2],
                           floatx4 (&acc)[8][4]) {
#pragma unroll
    for (int i = 0; i < 4; ++i)
#pragma unroll
        for (int j = 0; j < 2; ++j) {
            floatx4 c = acc[RQ * 4 + i][CQ * 2 + j];
            c = __builtin_amdgcn_mfma_f32_16x16x32_bf16(af[i][0], bq[j][0], c, 0, 0, 0);
            c = __builtin_amdgcn_mfma_f32_16x16x32_bf16(af[i][1], bq[j][1], c, 0, 0, 0);
            acc[RQ * 4 + i][CQ * 2 + j] = c;
        }
}

__device__ inline void stage_half(const bf16* gsrc, bf16* ldst, long rowK) {
    gl_lds16(gsrc,            ldst);
    gl_lds16(gsrc + 8 * rowK, ldst + 512);
}

__global__ __launch_bounds__(512, 2) void gemm256(
    const bf16* __restrict__ A, const bf16* __restrict__ Bt, void* __restrict__ C,
    int Ntot, int Ktot, int outf32) {
    __shared__ bf16 lds[2][2][2][128 * 64];   // [buf][A/B][half][r*64+c] = 128 KiB
    const int tid = threadIdx.x;
    const int w = tid >> 6, lane = tid & 63;
    const int quad = lane >> 4, l16 = lane & 15;
    const int wr = w >> 2, wc = w & 3;

    // XCD-aware bijective swizzle (T1)
    const int gx = gridDim.x;
    const int nwg = gx * gridDim.y;
    int orig = blockIdx.y * gx + blockIdx.x;
    int q8 = nwg >> 3, r8 = nwg & 7;
    int xcd = orig & 7, lid = orig >> 3;
    int wg = (xcd < r8 ? xcd * (q8 + 1) : r8 * (q8 + 1) + (xcd - r8) * q8) + lid;
    const long m0 = (long)(wg / gx) << 8;
    const long n0 = (long)(wg % gx) << 8;

    // staging: lane's pre-swizzled source granule (3-bit slot XOR with row&7)
    const long rowK = Ktot;
    const int srow = w * 16 + (lane >> 3);               // row within half, chunk0
    const int scol = ((lane & 7) ^ (lane >> 3)) << 3;    // pre-swizzled source col
    const bf16* baseA = A  + (m0 + srow) * rowK + scol;
    const bf16* baseB = Bt + (n0 + srow) * rowK + scol;
    const int d0 = w * 1024 + lane * 8;                  // LDS elems (lane*16B), linear

    // ds_read swizzle: col = ((ks*4+quad) ^ (row&7)) * 8, row&7 == l16&7
    const int m7 = l16 & 7;
    const int col0 = ((0 + quad) ^ m7) << 3;   // ks=0
    const int col1 = ((4 + quad) ^ m7) << 3;   // ks=1
    const int brow = (wc & 1) * 64;

    floatx4 acc[8][4];
#pragma unroll
    for (int i = 0; i < 8; ++i)
#pragma unroll
        for (int j = 0; j < 4; ++j)
#pragma unroll
            for (int r = 0; r < 4; ++r) acc[i][j][r] = 0.f;

    bf16x8 af[4][2], bq0[2][2], bq1[2][2];

    const int T = Ktot >> 6;
    // prologue: tile0 {A0,A1,B0,B1} -> buf0; tile1 {B0,B1} -> buf1
    stage_half(baseA,                   &lds[0][0][0][d0], rowK);
    stage_half(baseA + 128 * rowK,      &lds[0][0][1][d0], rowK);
    stage_half(baseB,                   &lds[0][1][0][d0], rowK);
    stage_half(baseB + 128 * rowK,      &lds[0][1][1][d0], rowK);
    stage_half(baseB + 64,              &lds[1][1][0][d0], rowK);
    stage_half(baseB + 128 * rowK + 64, &lds[1][1][1][d0], rowK);
    asm volatile("s_waitcnt vmcnt(4)" ::: "memory");   // tile0 landed
    barrier_();

    for (int t = 0; t < T; ++t) {
        const int cur = t & 1, nxt = cur ^ 1;
        const bf16* pa = &lds[cur][0][wr][0];
        const bf16* pb = &lds[cur][1][wc >> 1][0];
        const long koff  = (long)(t + 1) * 64;
        const long koff2 = (long)(t + 2) * 64;

        // ---- phase 1: A q0 + B q0 | stage (t+1).A0 ----
        lda<0>(pa, l16, col0, col1, af);
        ldb<0>(pb, brow, l16, col0, col1, bq0);
        if (t + 1 < T) stage_half(baseA + koff, &lds[nxt][0][0][d0], rowK);
        barrier_();
        asm volatile("s_waitcnt lgkmcnt(0)" ::: "memory");
        __builtin_amdgcn_sched_barrier(0);
        __builtin_amdgcn_s_setprio(1);
        mma<0, 0>(af, bq0, acc);
        __builtin_amdgcn_s_setprio(0);
        barrier_();

        // ---- phase 2: B q1 | stage (t+1).A1 ----
        ldb<1>(pb, brow, l16, col0, col1, bq1);
        if (t + 1 < T) stage_half(baseA + 128 * rowK + koff, &lds[nxt][0][1][d0], rowK);
        barrier_();
        asm volatile("s_waitcnt lgkmcnt(0)" ::: "memory");
        __builtin_amdgcn_sched_barrier(0);
        __builtin_amdgcn_s_setprio(1);
        mma<0, 1>(af, bq1, acc);
        __builtin_amdgcn_s_setprio(0);
        barrier_();

        // ---- phase 3: A q1 | stage (t+2).B0 ----
        lda<1>(pa, l16, col0, col1, af);
        if (t + 2 < T) stage_half(baseB + koff2, &lds[cur][1][0][d0], rowK);
        barrier_();
        asm volatile("s_waitcnt lgkmcnt(0)" ::: "memory");
        __builtin_amdgcn_sched_barrier(0);
        __builtin_amdgcn_s_setprio(1);
        mma<1, 0>(af, bq0, acc);
        __builtin_amdgcn_s_setprio(0);
        barrier_();

        // ---- phase 4: stage (t+2).B1 | counted vmcnt ----
        if (t + 2 < T) stage_half(baseB + 128 * rowK + koff2, &lds[cur][1][1][d0], rowK);
        barrier_();
        asm volatile("s_waitcnt lgkmcnt(0)" ::: "memory");
        __builtin_amdgcn_sched_barrier(0);
        __builtin_amdgcn_s_setprio(1);
        mma<1, 1>(af, bq1, acc);
        __builtin_amdgcn_s_setprio(0);
        if (t + 2 < T) asm volatile("s_waitcnt vmcnt(4)" ::: "memory");
        else           asm volatile("s_waitcnt vmcnt(0)" ::: "memory");
        barrier_();
    }

    // epilogue: C/D layout row = quad*4 + r, col = l16
#pragma unroll
    for (int ri = 0; ri < 8; ++ri)
#pragma unroll
        for (int j = 0; j < 4; ++j)
#pragma unroll
            for (int r = 0; r < 4; ++r) {
                long m = m0 + wr * 128 + ri * 16 + quad * 4 + r;
                long n = n0 + wc * 64 + j * 16 + l16;
                if (outf32) ((float*)C)[m * Ntot + n] = acc[ri][j][r];
                else        ((bf16*)C)[m * Ntot + n] = (bf16)acc[ri][j][r];
            }
}

// ---------------------------------------------------------------------------
// Flash attention v3: block-cooperative LDS staging of K/V tiles.
// Block = 4 waves sharing (b,hq); wave w owns q-rows [q0b + 16w, +16).
// Per 64-key tile: stage K[64][64]->Ks (pad 72), V[64dim][64key]->Vs (pad 72)
// with coalesced loads; all waves read MFMA fragments from LDS.
// Fixed-max softmax: p = exp(s/8 - 12) (scores bounded, no online rescale).
// ---------------------------------------------------------------------------
__global__ __launch_bounds__(256) void attn_kernel(
    const bf16* __restrict__ QKV,  // [M][3072]: q(rope'd) | k(rope'd) | v
    const bf16* __restrict__ Vt,   // [B][HKV][64][896]
    bf16* __restrict__ AO) {       // [M][2048]
    __shared__ bf16 Ks[64 * 72];
    __shared__ bf16 Vs[64 * 72];
    __shared__ bf16 Ps[4][16 * 72];
    const int tid  = threadIdx.x;
    const int wid  = tid >> 6, lane = tid & 63;
    const int quad = lane >> 4, c = lane & 15;
    const int b = blockIdx.z, hq = blockIdx.y, kvh = hq >> 2;
    const int q0b = blockIdx.x * 64;
    const int q0 = q0b + wid * 16;
    bf16* ps = &Ps[wid][0];

    const bf16* Qb = QKV + ((long)(b * L_ + q0)) * NQKV + hq * HD_;
    const bf16* Kb = QKV + ((long)(b * L_)) * NQKV + D_ + kvh * HD_;
    const bf16* Vb = Vt + ((long)(b * HKV_ + kvh)) * (HD_ * L_);

    bf16x8 qf0 = *(const bf16x8*)&Qb[(long)c * NQKV + quad * 8];
    bf16x8 qf1 = *(const bf16x8*)&Qb[(long)c * NQKV + 32 + quad * 8];

    float lsum[4];
    floatx4 o[4];
#pragma unroll
    for (int r = 0; r < 4; r++) lsum[r] = 0.f;
#pragma unroll
    for (int nt = 0; nt < 4; nt++)
#pragma unroll
        for (int r = 0; r < 4; r++) o[nt][r] = 0.f;

    int fe[4];  // exclusive frame-end per owned row (rows quad*4+r)
#pragma unroll
    for (int r = 0; r < 4; r++) { int l = q0 + quad * 4 + r; fe[r] = (l / 7 + 1) * 7; }
    const int kend = ((q0b + 63) / 7 + 1) * 7;   // block-max frame end, <= 896

    // staging coords: thread stages 16 B at rows srow / srow+32, chunk schunk
    const int srow = tid >> 3, schunk = (tid & 7) << 3;

    for (int k0 = 0; k0 < kend; k0 += 64) {
        // coalesced global loads (1 KB contiguous per wave per load)
        bf16x8 kg0 = *(const bf16x8*)&Kb[(long)(k0 + srow) * NQKV + schunk];
        bf16x8 kg1 = *(const bf16x8*)&Kb[(long)(k0 + 32 + srow) * NQKV + schunk];
        bf16x8 vg0 = *(const bf16x8*)&Vb[(long)srow * L_ + k0 + schunk];
        bf16x8 vg1 = *(const bf16x8*)&Vb[(long)(srow + 32) * L_ + k0 + schunk];
        __syncthreads();   // previous tile's reads done before overwrite
        *(bf16x8*)&Ks[srow * 72 + schunk]        = kg0;
        *(bf16x8*)&Ks[(srow + 32) * 72 + schunk] = kg1;
        *(bf16x8*)&Vs[srow * 72 + schunk]        = vg0;
        *(bf16x8*)&Vs[(srow + 32) * 72 + schunk] = vg1;
        __syncthreads();

        // QK^T: B-frag b[j] = K[key = n*16+c][d = quad*8+j (+32)]
        floatx4 s[4];
#pragma unroll
        for (int n = 0; n < 4; n++) {
#pragma unroll
            for (int r = 0; r < 4; r++) s[n][r] = 0.f;
            bf16x8 kf0 = *(bf16x8*)&Ks[(n * 16 + c) * 72 + quad * 8];
            bf16x8 kf1 = *(bf16x8*)&Ks[(n * 16 + c) * 72 + 32 + quad * 8];
            s[n] = __builtin_amdgcn_mfma_f32_16x16x32_bf16(qf0, kf0, s[n], 0, 0, 0);
            s[n] = __builtin_amdgcn_mfma_f32_16x16x32_bf16(qf1, kf1, s[n], 0, 0, 0);
        }
        // fixed-max softmax: p = exp(s/8 - 12); masked -> 0
#pragma unroll
        for (int n = 0; n < 4; n++) {
            const int key = k0 + n * 16 + c;
#pragma unroll
            for (int r = 0; r < 4; r++) {
                float e = __expf(fmaf(s[n][r], 0.125f, -12.0f));
                e = (key < fe[r]) ? e : 0.f;
                lsum[r] += e;
                ps[(quad * 4 + r) * 72 + n * 16 + c] = (bf16)e;
            }
        }
        // P A-frags (same-wave LDS round-trip) + PV from Vs
        bf16x8 pf0 = *(bf16x8*)&ps[c * 72 + quad * 8];
        bf16x8 pf1 = *(bf16x8*)&ps[c * 72 + 32 + quad * 8];
#pragma unroll
        for (int nt = 0; nt < 4; nt++) {
            bf16x8 vf0 = *(bf16x8*)&Vs[(nt * 16 + c) * 72 + quad * 8];
            bf16x8 vf1 = *(bf16x8*)&Vs[(nt * 16 + c) * 72 + 32 + quad * 8];
            o[nt] = __builtin_amdgcn_mfma_f32_16x16x32_bf16(pf0, vf0, o[nt], 0, 0, 0);
            o[nt] = __builtin_amdgcn_mfma_f32_16x16x32_bf16(pf1, vf1, o[nt], 0, 0, 0);
        }
    }
    // one cross-lane lsum reduction over the 16 c-lanes
#pragma unroll
    for (int r = 0; r < 4; r++) {
#pragma unroll
        for (int off = 1; off < 16; off <<= 1) lsum[r] += __shfl_xor(lsum[r], off);
    }
#pragma unroll
    for (int nt = 0; nt < 4; nt++)
#pragma unroll
        for (int r = 0; r < 4; r++) {
            int l = q0 + quad * 4 + r;
            AO[((long)(b * L_ + l)) * D_ + hq * HD_ + nt * 16 + c] = (bf16)(o[nt][r] / lsum[r]);
        }
}

// ---------------------------------------------------------------------------
extern "C" void kernel_launch(void* const* d_in, const int* in_sizes, int n_in,
                              void* d_out, int out_size, void* d_ws, size_t ws_size,
                              hipStream_t stream) {
    (void)in_sizes; (void)n_in; (void)out_size; (void)ws_size;
    const float* x  = (const float*)d_in[0];
    const float* wq = (const float*)d_in[1];
    const float* wk = (const float*)d_in[2];
    const float* wv = (const float*)d_in[3];
    const float* wo = (const float*)d_in[4];
    const int* pos  = (const int*)d_in[5];

    bf16* ws    = (bf16*)d_ws;
    bf16* xb    = ws;                   // [3584][2048] bf16 x  (reused as AO)
    bf16* wqkvT = ws + 7340032L;        // [3072][2048]  (wq^T | wk^T | wv^T)
    bf16* woT   = ws + 13631488L;       // [2048][2048]
    bf16* QKV   = ws + 17825792L;       // [3584][3072]
    bf16* Vt    = ws + 28835840L;       // [4][8][64][896]
    bf16* AO    = xb;
    float2* cs  = (float2*)(ws + 30670848L);  // [896][32]

    convert_to_bf16<<<dim3(7168), 256, 0, stream>>>(x, xb);
    rope_cs_kernel<<<dim3(112), dim3(256), 0, stream>>>(pos, cs);

    transpose_cvt<<<dim3(32, 32), 256, 0, stream>>>(wq, (ushort*)wqkvT, 2048, 2048);
    transpose_cvt<<<dim3(8, 32), 256, 0, stream>>>(wk, (ushort*)(wqkvT + 4194304L), 512, 2048);
    transpose_cvt<<<dim3(8, 32), 256, 0, stream>>>(wv, (ushort*)(wqkvT + 5242880L), 512, 2048);
    transpose_cvt<<<dim3(32, 32), 256, 0, stream>>>(wo, (ushort*)woT, 2048, 2048);

    // QKV projection: [3584][2048] x [3072][2048]^T -> [3584][3072] bf16
    gemm256<<<dim3(12, 14), 512, 0, stream>>>(xb, wqkvT, QKV, NQKV, D_, 0);

    rope_apply<<<dim3(4480), 256, 0, stream>>>(QKV, cs);

    // V cols of QKV -> Vt[b][h][64][896]
    transpose_u16<<<dim3(1, 14, 32), 256, 0, stream>>>(
        (const ushort*)(QKV + 2560), (ushort*)Vt, 3072, 896,
        896L * 3072, 64, 8L * 57344, 57344);

    attn_kernel<<<dim3(14, 32, 4), 256, 0, stream>>>(QKV, Vt, AO);

    // output projection: [3584][2048] x [2048][2048]^T -> [3584][2048] fp32
    gemm256<<<dim3(8, 14), 512, 0, stream>>>(AO, woT, d_out, D_, D_, 1);
}